// Round 3
// baseline (685.693 us; speedup 1.0000x reference)
//
#include <hip/hip_runtime.h>
#include <cmath>

// ---------------------------------------------------------------------------
// Fused 3D SSIM, separable Gaussian 11-tap, VALID. fp32 (2,1,192,192,192).
// One block = one 12^3 output tile. Single-t1 sequential-channel pipeline:
// LDS 35.9 KB -> 4 blocks/CU; 320-thread blocks balance the 264-item H phase.
// ---------------------------------------------------------------------------

#define WSZ 11
#define DIN 192
#define DOUTS 182
#define TO 12              // output tile edge
#define II 22              // input tile edge (TO + WSZ - 1)
#define NT 16              // tiles per axis: 16*12 = 192 >= 182
#define BT 320             // threads per block (5 waves)
static constexpr double SOUT = 2.0 * 182.0 * 182.0 * 182.0;  // 12,057,136

struct G11 { float g[WSZ]; };

__device__ __forceinline__ unsigned int enc_f(float f) {
    unsigned int u = __float_as_uint(f);
    return (u & 0x80000000u) ? ~u : (u | 0x80000000u);
}
__device__ __forceinline__ float dec_f(unsigned int u) {
    return (u & 0x80000000u) ? __uint_as_float(u & 0x7FFFFFFFu) : __uint_as_float(~u);
}

// ---------------------------------------------------------------------------
__global__ __launch_bounds__(256) void k_minmax(const float4* __restrict__ img1,
                                                int n4, unsigned int* mm) {
    float mx = -1e30f, mn = 1e30f;
    for (int i = blockIdx.x * blockDim.x + threadIdx.x; i < n4;
         i += gridDim.x * blockDim.x) {
        float4 v = img1[i];
        mx = fmaxf(mx, fmaxf(fmaxf(v.x, v.y), fmaxf(v.z, v.w)));
        mn = fminf(mn, fminf(fminf(v.x, v.y), fminf(v.z, v.w)));
    }
    #pragma unroll
    for (int o = 32; o; o >>= 1) {
        mx = fmaxf(mx, __shfl_down(mx, o));
        mn = fminf(mn, __shfl_down(mn, o));
    }
    __shared__ float smx[4], smn[4];
    int lane = threadIdx.x & 63, wv = threadIdx.x >> 6;
    if (lane == 0) { smx[wv] = mx; smn[wv] = mn; }
    __syncthreads();
    if (threadIdx.x == 0) {
        #pragma unroll
        for (int i = 1; i < 4; i++) { mx = fmaxf(mx, smx[i]); mn = fminf(mn, smn[i]); }
        atomicMax(&mm[0], enc_f(mx));
        atomicMin(&mm[1], enc_f(mn));
    }
}

// ---------------------------------------------------------------------------
// Load one 22-float W-row from global, zero-filling chunks past the array
// edge (those taps only feed discarded outputs). w0 is a multiple of 12 ->
// base is 16B aligned; chunks are float4-aligned.
__device__ __forceinline__ void load_row(const float* __restrict__ img,
                                         int n, int dr, int hr, int w0,
                                         float v[II]) {
    const float* p = img + ((n * DIN + dr) * DIN + hr) * DIN + w0;
    #pragma unroll
    for (int c = 0; c < 5; c++) {
        if (w0 + c * 4 + 3 < DIN) {   // wave-uniform (w0 uniform per block)
            float4 f = *reinterpret_cast<const float4*>(p + c * 4);
            v[c*4+0] = f.x; v[c*4+1] = f.y; v[c*4+2] = f.z; v[c*4+3] = f.w;
        } else {
            v[c*4+0] = v[c*4+1] = v[c*4+2] = v[c*4+3] = 0.f;
        }
    }
    if (w0 + 21 < DIN) { v[20] = p[20]; v[21] = p[21]; }
    else               { v[20] = 0.f;   v[21] = 0.f;   }
}

// W-conv of one channel -> t1 [x][z][y22].
// MODE 0: x (from i1);  MODE 1: x^2 (from i1);  MODE 2: x1*x2.
template <int MODE>
__device__ __forceinline__ void conv_w(const float* __restrict__ i1,
                                       const float* __restrict__ i2,
                                       int n, int d0, int h0, int w0,
                                       float* t1, const G11& gw, int tid) {
    for (int u = tid; u < II * II; u += BT) {
        int z = u / II, y = u - z * II;
        int dr = min(d0 + z, DIN - 1);
        int hr = min(h0 + y, DIN - 1);
        float v[II];
        load_row(i1, n, dr, hr, w0, v);
        if (MODE == 1) {
            #pragma unroll
            for (int j = 0; j < II; j++) v[j] = v[j] * v[j];
        } else if (MODE == 2) {
            float v2[II];
            load_row(i2, n, dr, hr, w0, v2);
            #pragma unroll
            for (int j = 0; j < II; j++) v[j] = v[j] * v2[j];
        }
        #pragma unroll
        for (int x = 0; x < TO; x++) {
            float a = 0.f;
            #pragma unroll
            for (int k = 0; k < WSZ; k++) a = fmaf(gw.g[k], v[x + k], a);
            t1[(x * II + z) * II + y] = a;
        }
    }
}

// H-conv: t1 [x][z][y22] -> t2 [y][x][z22]. 264 items, one round at BT=320.
__device__ __forceinline__ void conv_h(const float* t1, float* t2,
                                       const G11& gw, int tid) {
    if (tid < TO * II) {   // tid = x*22 + z
        float v[II];
        #pragma unroll
        for (int j = 0; j < 11; j++) {
            float2 f = reinterpret_cast<const float2*>(t1 + tid * II)[j];
            v[2*j] = f.x; v[2*j+1] = f.y;
        }
        int x = tid / II, z = tid - (tid / II) * II;
        #pragma unroll
        for (int oy = 0; oy < TO; oy++) {
            float a = 0.f;
            #pragma unroll
            for (int k = 0; k < WSZ; k++) a = fmaf(gw.g[k], v[oy + k], a);
            t2[(oy * TO + x) * II + z] = a;
        }
    }
}

// D-conv: t2 [y][x][z22] -> 12 outputs in registers (threads tid<144).
__device__ __forceinline__ void conv_d(const float* t2, float* dst,
                                       const G11& gw, int tid) {
    if (tid < TO * TO) {
        float v[II];
        #pragma unroll
        for (int j = 0; j < 11; j++) {
            float2 f = reinterpret_cast<const float2*>(t2 + tid * II)[j];
            v[2*j] = f.x; v[2*j+1] = f.y;
        }
        #pragma unroll
        for (int zz = 0; zz < TO; zz++) {
            float a = 0.f;
            #pragma unroll
            for (int k = 0; k < WSZ; k++) a = fmaf(gw.g[k], v[zz + k], a);
            dst[zz] = a;
        }
    }
}

// ---------------------------------------------------------------------------
__global__ __launch_bounds__(BT, 5) void k_ssim(const float* __restrict__ img1,
                                                const float* __restrict__ img2,
                                                const unsigned int* __restrict__ mm,
                                                double* __restrict__ sum, G11 gw) {
    __shared__ float t1[II * TO * II];  // 5808 floats
    __shared__ float t2[TO * TO * II];  // 3168 floats
    __shared__ float sred[5];

    int b  = blockIdx.x;
    int tw = b & 15, th = (b >> 4) & 15, td = (b >> 8) & 15, n = b >> 12;
    int w0 = tw * TO, h0 = th * TO, d0 = td * TO;
    int tid = threadIdx.x;

    float r[5][TO];  // mu1, mu2, E[x1^2], E[x2^2], E[x1x2]

    // channel order keeps back-to-back re-reads of the same image rows hot:
    // x1, x1^2 (img1), x2, x2^2 (img2), x1*x2 (both)
    conv_w<0>(img1, nullptr, n, d0, h0, w0, t1, gw, tid); __syncthreads();
    conv_h(t1, t2, gw, tid);                              __syncthreads();
    conv_d(t2, r[0], gw, tid);                            __syncthreads();

    conv_w<1>(img1, nullptr, n, d0, h0, w0, t1, gw, tid); __syncthreads();
    conv_h(t1, t2, gw, tid);                              __syncthreads();
    conv_d(t2, r[2], gw, tid);                            __syncthreads();

    conv_w<0>(img2, nullptr, n, d0, h0, w0, t1, gw, tid); __syncthreads();
    conv_h(t1, t2, gw, tid);                              __syncthreads();
    conv_d(t2, r[1], gw, tid);                            __syncthreads();

    conv_w<1>(img2, nullptr, n, d0, h0, w0, t1, gw, tid); __syncthreads();
    conv_h(t1, t2, gw, tid);                              __syncthreads();
    conv_d(t2, r[3], gw, tid);                            __syncthreads();

    conv_w<2>(img1, img2, n, d0, h0, w0, t1, gw, tid);    __syncthreads();
    conv_h(t1, t2, gw, tid);                              __syncthreads();
    conv_d(t2, r[4], gw, tid);

    // --- SSIM + reduction ---
    float maxv = dec_f(mm[0]);
    float minv = dec_f(mm[1]);
    float max_val = (maxv > 128.0f) ? 255.0f : 1.0f;
    float min_val = (minv < -0.5f) ? -1.0f : 0.0f;
    float L  = max_val - min_val;
    float C1 = 0.01f * L; C1 *= C1;
    float C2 = 0.03f * L; C2 *= C2;

    float local = 0.f;
    if (tid < TO * TO) {
        int y = tid / TO, x = tid - (tid / TO) * TO;
        int oh = h0 + y, ow = w0 + x;
        if (oh < DOUTS && ow < DOUTS) {
            #pragma unroll
            for (int zz = 0; zz < TO; zz++) {
                int od = d0 + zz;
                if (od < DOUTS) {
                    float mu1 = r[0][zz], mu2 = r[1][zz];
                    float mu1s = mu1 * mu1, mu2s = mu2 * mu2, mu12 = mu1 * mu2;
                    float s1  = r[2][zz] - mu1s;
                    float s2  = r[3][zz] - mu2s;
                    float s12 = r[4][zz] - mu12;
                    float v1  = 2.0f * s12 + C2;
                    float v2  = s1 + s2 + C2;
                    float num = (2.0f * mu12 + C1) * v1;
                    float den = (mu1s + mu2s + C1) * v2;
                    local += num / den;
                }
            }
        }
    }
    #pragma unroll
    for (int o = 32; o; o >>= 1) local += __shfl_down(local, o);
    if ((tid & 63) == 0) sred[tid >> 6] = local;
    __syncthreads();
    if (tid == 0)
        atomicAdd(sum, (double)(sred[0] + sred[1] + sred[2] + sred[3] + sred[4]));
}

// ---------------------------------------------------------------------------
__global__ void k_final(const double* __restrict__ sum, float* __restrict__ out) {
    out[0] = (float)(sum[0] / SOUT);
}

// ---------------------------------------------------------------------------
extern "C" void kernel_launch(void* const* d_in, const int* in_sizes, int n_in,
                              void* d_out, int out_size, void* d_ws, size_t ws_size,
                              hipStream_t stream) {
    const float* img1 = (const float*)d_in[0];
    const float* img2 = (const float*)d_in[1];
    float* out = (float*)d_out;

    char* ws = (char*)d_ws;
    double*       sum = (double*)ws;              // 8 B
    unsigned int* mm  = (unsigned int*)(ws + 8);  // 8 B

    // Gaussian weights: f64 compute, normalize, cast to f32 (matches ref).
    G11 g;
    {
        double gd[WSZ], s = 0.0;
        for (int i = 0; i < WSZ; i++) {
            double d = (double)(i - WSZ / 2);
            gd[i] = std::exp(-(d * d) / (2.0 * 1.5 * 1.5));
            s += gd[i];
        }
        for (int i = 0; i < WSZ; i++) g.g[i] = (float)(gd[i] / s);
    }

    int n_img = 2 * DIN * DIN * DIN;  // 14,155,776

    // init: sum=0.0, mm[0]=0 (enc -inf), mm[1]=0xFFFFFFFF (enc +inf)
    hipMemsetAsync(ws, 0, 12, stream);
    hipMemsetAsync(ws + 12, 0xFF, 4, stream);
    k_minmax<<<2048, 256, 0, stream>>>((const float4*)img1, n_img / 4, mm);
    k_ssim<<<2 * NT * NT * NT, BT, 0, stream>>>(img1, img2, mm, sum, g);
    k_final<<<1, 1, 0, stream>>>(sum, out);
}

// Round 4
// 404.858 us; speedup vs baseline: 1.6937x; 1.6937x over previous
//
#include <hip/hip_runtime.h>
#include <cmath>

// ---------------------------------------------------------------------------
// Fused 3D SSIM, separable Gaussian 11-tap, VALID. fp32 (2,1,192,192,192).
// z-streaming slab: block owns a 16x16 (H,W) output tile and marches along D
// over a 24-plane chunk. Per plane: W-conv (global->LDS, 5 channels from one
// load), 1 barrier, H-conv (LDS->regs), D-conv as a register shift-FMA
// pipeline (acc[5][11], no dynamic indexing). SSIM fused, one f64 atomic per
// block. Workspace use: 16 bytes.
// ---------------------------------------------------------------------------

#define WSZ 11
#define DIN 192
#define DOUTS 182
#define TH 16              // tile height (output rows)
#define TWD 16             // tile width  (output cols)
#define IH 26              // input rows per plane tile (TH + 10)
#define ZCH 24             // output planes per chunk
#define ZIN 34             // input planes per chunk (ZCH + 10)
#define NTH 12             // tiles per axis (12*16 = 192 >= 182)
#define ZC 8               // z-chunks (8*24 = 192 >= 182)
#define NBLK (NTH*NTH*2*ZC)  // 2304
static constexpr double SOUT = 2.0 * 182.0 * 182.0 * 182.0;  // 12,057,136

struct G11 { float g[WSZ]; };

__device__ __forceinline__ unsigned int enc_f(float f) {
    unsigned int u = __float_as_uint(f);
    return (u & 0x80000000u) ? ~u : (u | 0x80000000u);
}
__device__ __forceinline__ float dec_f(unsigned int u) {
    return (u & 0x80000000u) ? __uint_as_float(u & 0x7FFFFFFFu) : __uint_as_float(~u);
}

// ---------------------------------------------------------------------------
__global__ __launch_bounds__(256) void k_minmax(const float4* __restrict__ img1,
                                                int n4, unsigned int* mm) {
    float mx = -1e30f, mn = 1e30f;
    for (int i = blockIdx.x * blockDim.x + threadIdx.x; i < n4;
         i += gridDim.x * blockDim.x) {
        float4 v = img1[i];
        mx = fmaxf(mx, fmaxf(fmaxf(v.x, v.y), fmaxf(v.z, v.w)));
        mn = fminf(mn, fminf(fminf(v.x, v.y), fminf(v.z, v.w)));
    }
    #pragma unroll
    for (int o = 32; o; o >>= 1) {
        mx = fmaxf(mx, __shfl_down(mx, o));
        mn = fminf(mn, __shfl_down(mn, o));
    }
    __shared__ float smx[4], smn[4];
    int lane = threadIdx.x & 63, wv = threadIdx.x >> 6;
    if (lane == 0) { smx[wv] = mx; smn[wv] = mn; }
    __syncthreads();
    if (threadIdx.x == 0) {
        #pragma unroll
        for (int i = 1; i < 4; i++) { mx = fmaxf(mx, smx[i]); mn = fminf(mn, smn[i]); }
        atomicMax(&mm[0], enc_f(mx));
        atomicMin(&mm[1], enc_f(mn));
    }
}

// ---------------------------------------------------------------------------
// launch_bounds(256, 4): 4 waves/EU -> VGPR cap 128; acc[5][11]+working ~110.
__global__ __launch_bounds__(256, 4) void k_ssim(const float* __restrict__ img1,
                                                 const float* __restrict__ img2,
                                                 const unsigned int* __restrict__ mm,
                                                 double* __restrict__ sum, G11 gw) {
    __shared__ float tws[2][5][IH][TWD];  // double-buffered W-conv plane, 16.6 KB
    __shared__ float sred[4];

    int b   = blockIdx.x;
    int twi = b % NTH;
    int thi = (b / NTH) % NTH;
    int rest = b / (NTH * NTH);
    int tc  = rest % ZC;
    int n   = rest / ZC;                 // batch 0..1
    int ow0 = twi * TWD, oh0 = thi * TH, od0 = tc * ZCH;
    int tid = threadIdx.x;
    int y = tid >> 4, x = tid & 15;

    // SSIM constants (L from img1 min/max, computed by k_minmax)
    float maxv = dec_f(mm[0]);
    float minv = dec_f(mm[1]);
    float max_val = (maxv > 128.0f) ? 255.0f : 1.0f;
    float min_val = (minv < -0.5f) ? -1.0f : 0.0f;
    float L  = max_val - min_val;
    float C1 = 0.01f * L; C1 *= C1;
    float C2 = 0.03f * L; C2 *= C2;

    bool valid_xy = (oh0 + y < DOUTS) && (ow0 + x < DOUTS);

    // D-conv shift-register pipeline: after plane zi, acc[c][j] = partial sum
    // for output zo = zi - j over planes zo..zi. acc[c][10] completes at zi.
    float acc[5][WSZ];
    float local = 0.f;

    for (int zi = 0; zi < ZIN; zi++) {
        int buf = zi & 1;
        int d = min(od0 + zi, DIN - 1);  // clamped planes feed only masked zo

        // ---- W phase: 208 pair-items (h in [0,26), xop in [0,8)) ----
        if (tid < IH * (TWD / 2)) {
            int h = tid >> 3, xop = tid & 7;
            int hr = min(oh0 + h, DIN - 1);        // clamped rows feed masked oh
            int s  = min(ow0 + 2 * xop, DIN - TWD + 4);  // <=180, keeps loads in-bounds
            const float* p1 = img1 + (((n * DIN + d) * DIN + hr) * DIN + s);
            const float* p2 = img2 + (((n * DIN + d) * DIN + hr) * DIN + s);
            float v1[12], v2[12];
            #pragma unroll
            for (int q = 0; q < 6; q++) {          // even base -> float2 aligned
                float2 f1 = reinterpret_cast<const float2*>(p1)[q];
                float2 f2 = reinterpret_cast<const float2*>(p2)[q];
                v1[2*q] = f1.x; v1[2*q+1] = f1.y;
                v2[2*q] = f2.x; v2[2*q+1] = f2.y;
            }
            float a1[2] = {0.f,0.f}, a2[2] = {0.f,0.f};
            float a11[2] = {0.f,0.f}, a22[2] = {0.f,0.f}, a12[2] = {0.f,0.f};
            #pragma unroll
            for (int k = 0; k < WSZ; k++) {
                float g = gw.g[k];
                #pragma unroll
                for (int o = 0; o < 2; o++) {
                    float x1 = v1[k+o], x2 = v2[k+o];
                    float t1 = g * x1, t2 = g * x2;
                    a1[o] += t1; a2[o] += t2;
                    a11[o] = fmaf(t1, x1, a11[o]);
                    a22[o] = fmaf(t2, x2, a22[o]);
                    a12[o] = fmaf(t1, x2, a12[o]);
                }
            }
            int xo = 2 * xop;
            *(float2*)&tws[buf][0][h][xo] = make_float2(a1[0],  a1[1]);
            *(float2*)&tws[buf][1][h][xo] = make_float2(a2[0],  a2[1]);
            *(float2*)&tws[buf][2][h][xo] = make_float2(a11[0], a11[1]);
            *(float2*)&tws[buf][3][h][xo] = make_float2(a22[0], a22[1]);
            *(float2*)&tws[buf][4][h][xo] = make_float2(a12[0], a12[1]);
        }
        __syncthreads();   // single barrier per plane (double-buffered tws)

        // ---- H phase: every thread computes m[5] at its (y,x) ----
        float m[5];
        #pragma unroll
        for (int c = 0; c < 5; c++) {
            float a = 0.f;
            #pragma unroll
            for (int k = 0; k < WSZ; k++)
                a = fmaf(gw.g[k], tws[buf][c][y + k][x], a);
            m[c] = a;
        }

        // ---- D shift-FMA: acc[j] = g[j]*m + acc[j-1] (descending) ----
        #pragma unroll
        for (int c = 0; c < 5; c++) {
            #pragma unroll
            for (int j = WSZ - 1; j >= 1; j--)
                acc[c][j] = fmaf(gw.g[j], m[c], acc[c][j-1]);
            acc[c][0] = gw.g[0] * m[c];
        }

        // ---- SSIM for completed output plane zo = zi - 10 ----
        if (zi >= WSZ - 1) {
            int zo = od0 + zi - (WSZ - 1);
            if (zo < DOUTS) {            // uniform branch
                float mu1 = acc[0][10], mu2 = acc[1][10];
                float mu1s = mu1 * mu1, mu2s = mu2 * mu2, mu12 = mu1 * mu2;
                float s1  = acc[2][10] - mu1s;
                float s2  = acc[3][10] - mu2s;
                float s12 = acc[4][10] - mu12;
                float v1  = 2.0f * s12 + C2;
                float v2  = s1 + s2 + C2;
                float num = (2.0f * mu12 + C1) * v1;
                float den = (mu1s + mu2s + C1) * v2;
                float ss  = num / den;
                local += valid_xy ? ss : 0.f;
            }
        }
    }

    // ---- block reduction -> one f64 atomic ----
    #pragma unroll
    for (int o = 32; o; o >>= 1) local += __shfl_down(local, o);
    if ((tid & 63) == 0) sred[tid >> 6] = local;
    __syncthreads();
    if (tid == 0)
        atomicAdd(sum, (double)(sred[0] + sred[1] + sred[2] + sred[3]));
}

// ---------------------------------------------------------------------------
__global__ void k_final(const double* __restrict__ sum, float* __restrict__ out) {
    out[0] = (float)(sum[0] / SOUT);
}

// ---------------------------------------------------------------------------
extern "C" void kernel_launch(void* const* d_in, const int* in_sizes, int n_in,
                              void* d_out, int out_size, void* d_ws, size_t ws_size,
                              hipStream_t stream) {
    const float* img1 = (const float*)d_in[0];
    const float* img2 = (const float*)d_in[1];
    float* out = (float*)d_out;

    char* ws = (char*)d_ws;
    double*       sum = (double*)ws;              // 8 B
    unsigned int* mm  = (unsigned int*)(ws + 8);  // 8 B

    // Gaussian weights: f64 compute, normalize, cast to f32 (matches ref).
    G11 g;
    {
        double gd[WSZ], s = 0.0;
        for (int i = 0; i < WSZ; i++) {
            double d = (double)(i - WSZ / 2);
            gd[i] = std::exp(-(d * d) / (2.0 * 1.5 * 1.5));
            s += gd[i];
        }
        for (int i = 0; i < WSZ; i++) g.g[i] = (float)(gd[i] / s);
    }

    int n_img = 2 * DIN * DIN * DIN;  // 14,155,776

    // init: sum=0.0, mm[0]=0 (enc -inf), mm[1]=0xFFFFFFFF (enc +inf)
    hipMemsetAsync(ws, 0, 12, stream);
    hipMemsetAsync(ws + 12, 0xFF, 4, stream);
    k_minmax<<<2048, 256, 0, stream>>>((const float4*)img1, n_img / 4, mm);
    k_ssim<<<NBLK, 256, 0, stream>>>(img1, img2, mm, sum, g);
    k_final<<<1, 1, 0, stream>>>(sum, out);
}

// Round 5
// 374.712 us; speedup vs baseline: 1.8299x; 1.0804x over previous
//
#include <hip/hip_runtime.h>
#include <cmath>

// ---------------------------------------------------------------------------
// Fused 3D SSIM, separable Gaussian 11-tap, VALID. fp32 (2,1,192,192,192).
// z-streaming slab, x-paired threads + packed-fp32 (v_pk_fma_f32) math:
//   tile 32(x) x 16(y), 256 threads, thread owns x-pair; acc[5][11] float2.
//   W-phase packs (img1,img2) as the vector lane-pair; H-phase reads LDS as
//   ds_read_b64; D-conv is a packed shift-FMA pipeline. 1 barrier/plane.
// ---------------------------------------------------------------------------

#define WSZ 11
#define DIN 192
#define DOUTS 182
#define TH 16              // tile height (output rows, y)
#define TWD 32             // tile width  (output cols, x)
#define IHR 26             // input rows per plane tile (TH + 10)
#define ZCH 24             // output planes per chunk
#define ZIN 34             // input planes per chunk (ZCH + 10)
#define NTX 6              // x tiles (6*32 = 192)
#define NTY 12             // y tiles (12*16 = 192)
#define ZC 8               // z-chunks (8*24 = 192)
#define NBLK (NTX*NTY*2*ZC)  // 1152
static constexpr double SOUT = 2.0 * 182.0 * 182.0 * 182.0;  // 12,057,136

typedef float v2f __attribute__((ext_vector_type(2)));

struct G11 { float g[WSZ]; };

__device__ __forceinline__ v2f pkfma(float g, v2f v, v2f a) {
    v2f gg = {g, g};
    return __builtin_elementwise_fma(gg, v, a);
}

__device__ __forceinline__ unsigned int enc_f(float f) {
    unsigned int u = __float_as_uint(f);
    return (u & 0x80000000u) ? ~u : (u | 0x80000000u);
}
__device__ __forceinline__ float dec_f(unsigned int u) {
    return (u & 0x80000000u) ? __uint_as_float(u & 0x7FFFFFFFu) : __uint_as_float(~u);
}

// ---------------------------------------------------------------------------
__global__ void k_init(unsigned int* mm, double* sum) {
    sum[0] = 0.0;
    mm[0] = 0u;           // encoded -inf (max accumulator)
    mm[1] = 0xFFFFFFFFu;  // encoded +inf (min accumulator)
}

// ---------------------------------------------------------------------------
__global__ __launch_bounds__(256) void k_minmax(const float4* __restrict__ img1,
                                                int n4, unsigned int* mm) {
    float mx = -1e30f, mn = 1e30f;
    for (int i = blockIdx.x * blockDim.x + threadIdx.x; i < n4;
         i += gridDim.x * blockDim.x) {
        float4 v = img1[i];
        mx = fmaxf(mx, fmaxf(fmaxf(v.x, v.y), fmaxf(v.z, v.w)));
        mn = fminf(mn, fminf(fminf(v.x, v.y), fminf(v.z, v.w)));
    }
    #pragma unroll
    for (int o = 32; o; o >>= 1) {
        mx = fmaxf(mx, __shfl_down(mx, o));
        mn = fminf(mn, __shfl_down(mn, o));
    }
    __shared__ float smx[4], smn[4];
    int lane = threadIdx.x & 63, wv = threadIdx.x >> 6;
    if (lane == 0) { smx[wv] = mx; smn[wv] = mn; }
    __syncthreads();
    if (threadIdx.x == 0) {
        #pragma unroll
        for (int i = 1; i < 4; i++) { mx = fmaxf(mx, smx[i]); mn = fminf(mn, smn[i]); }
        atomicMax(&mm[0], enc_f(mx));
        atomicMin(&mm[1], enc_f(mn));
    }
}

// ---------------------------------------------------------------------------
// launch_bounds(256, 3): 3 waves/EU -> VGPR cap ~170 (acc 110 + working ~50).
__global__ __launch_bounds__(256, 3) void k_ssim(const float* __restrict__ img1,
                                                 const float* __restrict__ img2,
                                                 const unsigned int* __restrict__ mm,
                                                 double* __restrict__ sum, G11 gw) {
    __shared__ float tws[2][5][IHR][TWD];  // double-buffered W-conv plane, 33.3 KB
    __shared__ float sred[4];

    int b   = blockIdx.x;
    int twi = b % NTX;
    int thi = (b / NTX) % NTY;
    int rest = b / (NTX * NTY);
    int tc  = rest % ZC;
    int n   = rest / ZC;                 // batch 0..1
    int ow0 = twi * TWD, oh0 = thi * TH, od0 = tc * ZCH;
    int tid = threadIdx.x;
    int y = tid >> 4, xg = tid & 15;     // thread owns outputs (y, 2xg), (y, 2xg+1)
    int x0 = 2 * xg;

    // SSIM constants (L from img1 min/max, computed by k_minmax)
    float maxv = dec_f(mm[0]);
    float minv = dec_f(mm[1]);
    float max_val = (maxv > 128.0f) ? 255.0f : 1.0f;
    float min_val = (minv < -0.5f) ? -1.0f : 0.0f;
    float L  = max_val - min_val;
    float C1 = 0.01f * L; C1 *= C1;
    float C2 = 0.03f * L; C2 *= C2;

    bool vy  = (oh0 + y < DOUTS);
    bool vx0 = vy && (ow0 + x0 < DOUTS);
    bool vx1 = vy && (ow0 + x0 + 1 < DOUTS);

    // D-conv packed shift pipeline: acc[c][j] covers output zo = zi - j.
    v2f acc[5][WSZ];
    float local = 0.f;

    for (int zi = 0; zi < ZIN; zi++) {
        int buf = zi & 1;
        int d = min(od0 + zi, DIN - 1);  // clamped planes feed only masked zo

        // ---- W phase: 416 pair-items (h in [0,26), xp in [0,16)) ----
        for (int u = tid; u < IHR * 16; u += 256) {
            int h = u >> 4, xp = u & 15;
            int hr = min(oh0 + h, DIN - 1);          // clamped rows -> masked oh
            int s  = min(ow0 + 2 * xp, DIN - 12);    // even, loads stay in-bounds
            const float2* p1 = (const float2*)(img1 + (((n * DIN + d) * DIN + hr) * DIN + s));
            const float2* p2 = (const float2*)(img2 + (((n * DIN + d) * DIN + hr) * DIN + s));
            v2f p[12];                               // lane-pair = (img1, img2)
            #pragma unroll
            for (int q = 0; q < 6; q++) {
                float2 f1 = p1[q];
                float2 f2 = p2[q];
                p[2*q]   = (v2f){f1.x, f2.x};
                p[2*q+1] = (v2f){f1.y, f2.y};
            }
            v2f amu[2] = {{0.f,0.f},{0.f,0.f}};      // (mu1, mu2) per output
            v2f asq[2] = {{0.f,0.f},{0.f,0.f}};      // (E11, E22) per output
            float a12[2] = {0.f, 0.f};               // E12 per output
            #pragma unroll
            for (int k = 0; k < WSZ; k++) {
                float g = gw.g[k];
                #pragma unroll
                for (int o = 0; o < 2; o++) {
                    v2f e = p[k + o];
                    v2f t = (v2f){g, g} * e;         // pk_mul
                    amu[o] += t;                     // pk_add
                    asq[o] = __builtin_elementwise_fma(t, e, asq[o]);  // pk_fma
                    a12[o] = fmaf(t.x, e.y, a12[o]); // cross term
                }
            }
            int xo = 2 * xp;
            *(v2f*)&tws[buf][0][h][xo] = (v2f){amu[0].x, amu[1].x};
            *(v2f*)&tws[buf][1][h][xo] = (v2f){amu[0].y, amu[1].y};
            *(v2f*)&tws[buf][2][h][xo] = (v2f){asq[0].x, asq[1].x};
            *(v2f*)&tws[buf][3][h][xo] = (v2f){asq[0].y, asq[1].y};
            *(v2f*)&tws[buf][4][h][xo] = (v2f){a12[0],   a12[1]};
        }
        __syncthreads();   // single barrier per plane (double-buffered tws)

        // ---- H phase: packed over the x-pair, ds_read_b64 per (c,k) ----
        v2f m[5];
        #pragma unroll
        for (int c = 0; c < 5; c++) {
            v2f a = {0.f, 0.f};
            #pragma unroll
            for (int k = 0; k < WSZ; k++) {
                v2f vv = *(const v2f*)&tws[buf][c][y + k][x0];
                a = pkfma(gw.g[k], vv, a);
            }
            m[c] = a;
        }

        // ---- D shift-FMA (packed): acc[j] = g[j]*m + acc[j-1] ----
        #pragma unroll
        for (int c = 0; c < 5; c++) {
            #pragma unroll
            for (int j = WSZ - 1; j >= 1; j--)
                acc[c][j] = pkfma(gw.g[j], m[c], acc[c][j-1]);
            acc[c][0] = (v2f){gw.g[0], gw.g[0]} * m[c];
        }

        // ---- SSIM for completed output plane zo = zi - 10 ----
        if (zi >= WSZ - 1) {
            int zo = od0 + zi - (WSZ - 1);
            if (zo < DOUTS) {            // uniform branch
                v2f mu1 = acc[0][10], mu2 = acc[1][10];
                v2f mu1s = mu1 * mu1, mu2s = mu2 * mu2, mu12 = mu1 * mu2;
                v2f s1  = acc[2][10] - mu1s;
                v2f s2  = acc[3][10] - mu2s;
                v2f s12 = acc[4][10] - mu12;
                v2f c2v = {C2, C2};
                v2f v1  = (v2f){2.f,2.f} * s12 + c2v;
                v2f v2  = s1 + s2 + c2v;
                v2f c1v = {C1, C1};
                v2f num = ((v2f){2.f,2.f} * mu12 + c1v) * v1;
                v2f den = (mu1s + mu2s + c1v) * v2;
                v2f ss  = num / den;
                if (vx0) local += ss.x;
                if (vx1) local += ss.y;
            }
        }
    }

    // ---- block reduction -> one f64 atomic ----
    #pragma unroll
    for (int o = 32; o; o >>= 1) local += __shfl_down(local, o);
    if ((tid & 63) == 0) sred[tid >> 6] = local;
    __syncthreads();
    if (tid == 0)
        atomicAdd(sum, (double)(sred[0] + sred[1] + sred[2] + sred[3]));
}

// ---------------------------------------------------------------------------
__global__ void k_final(const double* __restrict__ sum, float* __restrict__ out) {
    out[0] = (float)(sum[0] / SOUT);
}

// ---------------------------------------------------------------------------
extern "C" void kernel_launch(void* const* d_in, const int* in_sizes, int n_in,
                              void* d_out, int out_size, void* d_ws, size_t ws_size,
                              hipStream_t stream) {
    const float* img1 = (const float*)d_in[0];
    const float* img2 = (const float*)d_in[1];
    float* out = (float*)d_out;

    char* ws = (char*)d_ws;
    double*       sum = (double*)ws;              // 8 B
    unsigned int* mm  = (unsigned int*)(ws + 8);  // 8 B

    // Gaussian weights: f64 compute, normalize, cast to f32 (matches ref).
    G11 g;
    {
        double gd[WSZ], s = 0.0;
        for (int i = 0; i < WSZ; i++) {
            double d = (double)(i - WSZ / 2);
            gd[i] = std::exp(-(d * d) / (2.0 * 1.5 * 1.5));
            s += gd[i];
        }
        for (int i = 0; i < WSZ; i++) g.g[i] = (float)(gd[i] / s);
    }

    int n_img = 2 * DIN * DIN * DIN;  // 14,155,776

    k_init<<<1, 1, 0, stream>>>(mm, sum);
    k_minmax<<<2048, 256, 0, stream>>>((const float4*)img1, n_img / 4, mm);
    k_ssim<<<NBLK, 256, 0, stream>>>(img1, img2, mm, sum, g);
    k_final<<<1, 1, 0, stream>>>(sum, out);
}